// Round 10
// baseline (2439.399 us; speedup 1.0000x reference)
//
#include <hip/hip_runtime.h>
#include <hip/hip_bf16.h>
#include <math.h>

// Problem constants
#define BATCH   256
#define T_STEPS 4096
#define IN_DIM  28
#define HID     128
#define GATES   512   // 4*HID
#define OUT_DIM 10

#define HPAD    16                    // ushort pad: buf/par regions hit different banks
#define PARSTRIDE (HID + HPAD)        // ushorts between par=0 and par=1 regions
#define BUFSTRIDE (2 * PARSTRIDE)     // ushorts between buf 0 and buf 1

typedef short bf16x8 __attribute__((ext_vector_type(8)));  // 8 bf16 in 4 VGPRs
typedef float f32x4  __attribute__((ext_vector_type(4)));

#define SGB __builtin_amdgcn_sched_group_barrier
// LLVM SchedGroupMask: VALU=0x2, MFMA=0x8, DS_READ=0x100

#define LOG2E  1.44269504f
#define LOG2E2 2.88539008f

__device__ __forceinline__ float frcp_fast(float x) {
    return __builtin_amdgcn_rcpf(x);
}

__device__ __forceinline__ unsigned short f2bf(float f) {
    __hip_bfloat16 h = __float2bfloat16(f);   // RNE
    return __builtin_bit_cast(unsigned short, h);
}
__device__ __forceinline__ float bf2f(unsigned short u) {
    return __bfloat162float(__builtin_bit_cast(__hip_bfloat16, u));
}

__device__ __forceinline__ float sigm(float x) {
    float e = __builtin_exp2f(x * -LOG2E);
    return frcp_fast(1.0f + e);
}
__device__ __forceinline__ float tanh_fast(float x) {
    // tanh(x) = 1 - 2/(1+e^{2x}) — exact at both infinities
    float e = __builtin_exp2f(x * LOG2E2);
    return 1.0f - 2.0f * frcp_fast(1.0f + e);
}

// ---------------------------------------------------------------------------
// Kernel 1: input projection for batch element 255, UNIT-MAJOR output:
// gx2[t, u, gt] = dot(x255[t,:], w_ih[gt*128+u,:]) + b_ih[..] + b_hh[..]
// ---------------------------------------------------------------------------
__global__ __launch_bounds__(GATES) void k_inproj(const float* __restrict__ x255,
                                                  const float* __restrict__ w_ih,
                                                  const float* __restrict__ b_ih,
                                                  const float* __restrict__ b_hh,
                                                  float* __restrict__ gx2) {
    const int t = blockIdx.x;
    const int g = threadIdx.x;          // gate row 0..511 (i|f|g|o blocks of 128)
    const int unit = g & (HID - 1);
    const int quad = g >> 7;
    __shared__ float xs[IN_DIM];
    if (g < IN_DIM) xs[g] = x255[t * IN_DIM + g];
    __syncthreads();
    float acc = b_ih[g] + b_hh[g];
    const float* __restrict__ wr = w_ih + g * IN_DIM;
#pragma unroll
    for (int k = 0; k < IN_DIM; ++k) acc += wr[k] * xs[k];
    gx2[t * GATES + unit * 4 + quad] = acc;
}

// ---------------------------------------------------------------------------
// Kernel 2 (main): MFMA LSTM scan — 512 threads (8 waves), unit-major,
// operand-swapped (R7-verified): A = h (EVEN rows h_hi, ODD rows h_lo),
// B = W_hh (col n = unit). Lane: col cidx = its unit; reg0 = hi-part,
// reg1 = lo-part -> pre = a[0]+a[1]+gx, static regs.
//
// R10 — critical-path restructure (R9 lesson: step is DEPENDENCY-bound,
// not issue-bound; 3 rounds of issue-interleaving moved ~2% total):
//  - dual accumulators per gate (even/odd kt): dependent-MFMA chain depth
//    4 -> 2 (+2 epilogue adds per gate)
//  - gate order f,i,g,o with the cell chain threaded: f-act+fv*c under
//    i-MFMAs, i-act under g-MFMAs, g-act + c=fma + tanh(c) under o-MFMAs.
//    Post-last-MFMA tail = p3-sum, sigm(o), h, cvt, write (~55 cy, was ~110).
//  - all lanes compute hi/lo; writes distributed q0->hi, q1->lo, q2->hs.
// ---------------------------------------------------------------------------
__global__ __attribute__((amdgpu_flat_work_group_size(512, 512),
                          amdgpu_waves_per_eu(2, 2)))
void k_scan_mfma(const float* __restrict__ gx2,
                 const float* __restrict__ w_hh,
                 float* __restrict__ hs) {
    const int tid   = threadIdx.x;
    const int w     = tid >> 6;         // wave 0..7
    const int l     = tid & 63;         // lane 0..63
    const int q     = l >> 4;           // k-group / D row-group 0..3
    const int cidx  = l & 15;           // D column = unit within wave
    const int par   = cidx & 1;         // A-row parity: 0 -> h_hi, 1 -> h_lo
    const int ubase = w * 16;
    const int u     = ubase + cidx;     // unit this lane finalizes

    __shared__ __align__(16) unsigned short hb[2 * BUFSTRIDE];

    // ---- one-time: B-frags wb_[gate_type][kt] (64 VGPRs) ----
    // lane l holds B[k = kt*32 + q*8 + j][col = cidx] = W_hh[gt*128+u][k]
    bf16x8 wb_[4][4];
#pragma unroll
    for (int gt = 0; gt < 4; ++gt) {
        const int row = gt * HID + u;
        const float* __restrict__ wr = w_hh + row * HID;
#pragma unroll
        for (int kt = 0; kt < 4; ++kt) {
            const int k0 = kt * 32 + q * 8;
            bf16x8 v;
#pragma unroll
            for (int j = 0; j < 8; ++j) v[j] = (short)f2bf(wr[k0 + j]);
            wb_[gt][kt] = v;
        }
    }

    // zero both buffers (both parities)
    if (tid < HID) {
        hb[0 * BUFSTRIDE + 0 * PARSTRIDE + tid] = 0;
        hb[0 * BUFSTRIDE + 1 * PARSTRIDE + tid] = 0;
        hb[1 * BUFSTRIDE + 0 * PARSTRIDE + tid] = 0;
        hb[1 * BUFSTRIDE + 1 * PARSTRIDE + tid] = 0;
    }
    float c = 0.0f;                     // cell state (4x replicated per unit)
    const unsigned short* __restrict__ hq = &hb[par * PARSTRIDE + q * 8]; // A-frag base
    unsigned short* __restrict__ wpt = &hb[u];                            // writer base
    const f32x4 ZQ = {0.f, 0.f, 0.f, 0.f};   // persistent zero C-operand

    float4 gnext = *reinterpret_cast<const float4*>(gx2 + u * 4);  // t=0
    __syncthreads();

// gate type indices: i=0, f=1, g=2, o=3
#define MF(A, G, K, C_) __builtin_amdgcn_mfma_f32_16x16x32_bf16((A), wb_[G][K], (C_), 0, 0, 0)

#define LSTM_STEP(T, RB, WB)                                                   \
    {                                                                          \
        float4 gcur = gnext;                                                   \
        if ((T) + 1 < T_STEPS)                                                 \
            gnext = *reinterpret_cast<const float4*>(gx2 + ((T) + 1) * GATES + u * 4); \
        bf16x8 af0 = *reinterpret_cast<const bf16x8*>(hq + (RB) * BUFSTRIDE + 0 * 32); \
        bf16x8 af1 = *reinterpret_cast<const bf16x8*>(hq + (RB) * BUFSTRIDE + 1 * 32); \
        bf16x8 af2 = *reinterpret_cast<const bf16x8*>(hq + (RB) * BUFSTRIDE + 2 * 32); \
        bf16x8 af3 = *reinterpret_cast<const bf16x8*>(hq + (RB) * BUFSTRIDE + 3 * 32); \
        /* f-gate: dual 2-chains (even kt / odd kt) */                         \
        f32x4 fe = MF(af0, 1, 0, ZQ);                                          \
        f32x4 fo = MF(af1, 1, 1, ZQ);                                          \
        fe = MF(af2, 1, 2, fe);                                                \
        fo = MF(af3, 1, 3, fo);                                                \
        /* i-gate starts; f-activation + fv*c threads under it */              \
        f32x4 ie = MF(af0, 0, 0, ZQ);                                          \
        f32x4 io = MF(af1, 0, 1, ZQ);                                          \
        float p1 = ((fe[0] + fe[1]) + (fo[0] + fo[1])) + gcur.y;               \
        float ef = __builtin_exp2f(p1 * -LOG2E);                               \
        float fv = frcp_fast(1.0f + ef);                                       \
        float fc = fv * c;                                                     \
        ie = MF(af2, 0, 2, ie);                                                \
        io = MF(af3, 0, 3, io);                                                \
        /* g-gate starts; i-activation threads under it */                     \
        f32x4 ge = MF(af0, 2, 0, ZQ);                                          \
        f32x4 go = MF(af1, 2, 1, ZQ);                                          \
        float p0 = ((ie[0] + ie[1]) + (io[0] + io[1])) + gcur.x;               \
        float ei = __builtin_exp2f(p0 * -LOG2E);                               \
        float iv = frcp_fast(1.0f + ei);                                       \
        ge = MF(af2, 2, 2, ge);                                                \
        go = MF(af3, 2, 3, go);                                                \
        /* o-gate starts; g-act + c update + tanh(c) thread under it */        \
        f32x4 oe = MF(af0, 3, 0, ZQ);                                          \
        f32x4 oo = MF(af1, 3, 1, ZQ);                                          \
        float p2 = ((ge[0] + ge[1]) + (go[0] + go[1])) + gcur.z;               \
        float eg = __builtin_exp2f(p2 * LOG2E2);                               \
        float gv = __builtin_fmaf(-2.0f, frcp_fast(1.0f + eg), 1.0f);          \
        float cn = __builtin_fmaf(iv, gv, fc);                                 \
        c = cn;                                                                \
        float ec = __builtin_exp2f(cn * LOG2E2);                               \
        float th = __builtin_fmaf(-2.0f, frcp_fast(1.0f + ec), 1.0f);          \
        oe = MF(af2, 3, 2, oe);                                                \
        oo = MF(af3, 3, 3, oo);                                                \
        /* minimal tail: o-activation, h, cvt, write */                        \
        float p3 = ((oe[0] + oe[1]) + (oo[0] + oo[1])) + gcur.w;               \
        float eo = __builtin_exp2f(p3 * -LOG2E);                               \
        float ov = frcp_fast(1.0f + eo);                                       \
        float h = ov * th;                                                     \
        unsigned short hi = f2bf(h);                                           \
        if (q == 0) wpt[(WB) * BUFSTRIDE] = hi;                                \
        if (q == 1) wpt[(WB) * BUFSTRIDE + PARSTRIDE] = f2bf(h - bf2f(hi));    \
        if (q == 2) hs[(T) * HID + u] = h;                                     \
        /* gentle pins matching the f,i,g,o rhythm */                          \
        SGB(0x100, 4, 0);                                                      \
        SGB(0x008, 6, 0); SGB(0x002, 8, 0);                                    \
        SGB(0x008, 4, 0); SGB(0x002, 6, 0);                                    \
        SGB(0x008, 4, 0); SGB(0x002, 14, 0);                                   \
        SGB(0x008, 2, 0);                                                      \
        __syncthreads();                                                       \
    }

    for (int t = 0; t < T_STEPS; t += 2) {
        LSTM_STEP(t, 1, 0);       // even step: read buf1 (zeroed at t=0), write buf0
        LSTM_STEP(t + 1, 0, 1);   // odd step: read buf0, write buf1
    }
#undef LSTM_STEP
#undef MF
}

// ---------------------------------------------------------------------------
// Fallback scan (fused input projection, f32 VALU) — only if d_ws too small.
// ---------------------------------------------------------------------------
__global__ __launch_bounds__(GATES) void k_scan_valu(const float* __restrict__ w_hh,
                                                     float* __restrict__ hs,
                                                     const float* __restrict__ x255,
                                                     const float* __restrict__ w_ih,
                                                     const float* __restrict__ b_ih,
                                                     const float* __restrict__ b_hh) {
    const int g    = threadIdx.x;
    const int quad = g >> 7;

    __shared__ float h_sh[HID];
    __shared__ float act_sh[GATES];
    __shared__ float xs[IN_DIM];

    float4 wv[HID / 4];
    const float4* __restrict__ wrow = reinterpret_cast<const float4*>(w_hh + g * HID);
#pragma unroll
    for (int k = 0; k < HID / 4; ++k) wv[k] = wrow[k];

    float bsum = b_ih[g] + b_hh[g];
    float wih[IN_DIM];
#pragma unroll
    for (int k = 0; k < IN_DIM; ++k) wih[k] = w_ih[g * IN_DIM + k];

    if (g < HID) h_sh[g] = 0.0f;
    float c = 0.0f;
    __syncthreads();

    for (int t = 0; t < T_STEPS; ++t) {
        __syncthreads();
        if (g < IN_DIM) xs[g] = x255[t * IN_DIM + g];
        __syncthreads();
        float a0 = bsum, a1 = 0.0f, a2 = 0.0f, a3 = 0.0f;
#pragma unroll
        for (int k = 0; k < IN_DIM; ++k) a0 += wih[k] * xs[k];

        const float4* __restrict__ h4 = reinterpret_cast<const float4*>(h_sh);
#pragma unroll
        for (int k = 0; k < HID / 4; ++k) {
            float4 hv = h4[k];
            a0 += wv[k].x * hv.x;
            a1 += wv[k].y * hv.y;
            a2 += wv[k].z * hv.z;
            a3 += wv[k].w * hv.w;
        }
        float pre = (a0 + a1) + (a2 + a3);
        float a = (quad == 2) ? tanh_fast(pre) : sigm(pre);
        act_sh[g] = a;
        __syncthreads();

        if (g < HID) {
            float iv = act_sh[g];
            float fv = act_sh[HID + g];
            float gv = act_sh[2 * HID + g];
            float ov = act_sh[3 * HID + g];
            c = fv * c + iv * gv;
            float h = ov * tanh_fast(c);
            h_sh[g] = h;
            hs[t * HID + g] = h;
        }
        __syncthreads();
    }
}

// ---------------------------------------------------------------------------
// Kernel 3: final FC — out[t, o] = dot(hs[t, :], w_fc[o, :]) + b_fc[o]
// ---------------------------------------------------------------------------
__global__ __launch_bounds__(256) void k_fc(const float* __restrict__ hs,
                                            const float* __restrict__ w_fc,
                                            const float* __restrict__ b_fc,
                                            float* __restrict__ out) {
    const int idx = blockIdx.x * blockDim.x + threadIdx.x;
    if (idx >= T_STEPS * OUT_DIM) return;
    const int t = idx / OUT_DIM;
    const int o = idx - t * OUT_DIM;
    const float* __restrict__ hrow = hs + t * HID;
    const float* __restrict__ wrow = w_fc + o * HID;
    float acc = b_fc[o];
#pragma unroll 8
    for (int k = 0; k < HID; ++k) acc += hrow[k] * wrow[k];
    out[idx] = acc;
}

// ---------------------------------------------------------------------------
extern "C" void kernel_launch(void* const* d_in, const int* in_sizes, int n_in,
                              void* d_out, int out_size, void* d_ws, size_t ws_size,
                              hipStream_t stream) {
    const float* x    = (const float*)d_in[0];  // [B, T, I]
    const float* w_ih = (const float*)d_in[1];  // [4H, I]
    const float* w_hh = (const float*)d_in[2];  // [4H, H]
    const float* b_ih = (const float*)d_in[3];  // [4H]
    const float* b_hh = (const float*)d_in[4];  // [4H]
    const float* w_fc = (const float*)d_in[5];  // [OUT, H]
    const float* b_fc = (const float*)d_in[6];  // [OUT]
    float* out = (float*)d_out;                 // [T, OUT]

    // Only batch element B-1 is observable in the reference output.
    const float* x255 = x + (size_t)(BATCH - 1) * T_STEPS * IN_DIM;

    float* hs = (float*)d_ws;                                  // 4096*128 f32 = 2 MB
    float* gx2 = hs + (size_t)T_STEPS * HID;                   // 4096*512 f32 = 8 MB (unit-major)
    const size_t need_full = (size_t)(T_STEPS * HID + T_STEPS * GATES) * sizeof(float);

    if (ws_size >= need_full) {
        k_inproj<<<T_STEPS, GATES, 0, stream>>>(x255, w_ih, b_ih, b_hh, gx2);
        k_scan_mfma<<<1, GATES, 0, stream>>>(gx2, w_hh, hs);
    } else {
        k_scan_valu<<<1, GATES, 0, stream>>>(w_hh, hs, x255, w_ih, b_ih, b_hh);
    }

    const int n = T_STEPS * OUT_DIM;
    k_fc<<<(n + 255) / 256, 256, 0, stream>>>(hs, w_fc, b_fc, out);
}